// Round 14
// baseline (73.514 us; speedup 1.0000x reference)
//
#include <hip/hip_runtime.h>

#pragma clang fp contract(off)

#define N_PTS   16384
#define N_SEEDS 20
#define KP1     11      // K+1, K=10
#define NBIN    512     // bits(d2) >> 22 : exponent + 1 mantissa bit
#define NREP    32      // hist[bin*32 + (t&31)] -> bank == t&31 (conflict-free)
#define CAP     4096    // candidate buffer; also LDS pad: >80KB total -> 1 block/CU
#define NKNN    3       // knn-role blocks per batch

typedef unsigned long long u64;
typedef unsigned int       u32;

__device__ __forceinline__ u64 shfl_xor_u64(u64 v, int off) {
    int lo = __shfl_xor((int)(u32)(v & 0xffffffffull), off);
    int hi = __shfl_xor((int)(u32)(v >> 32), off);
    return ((u64)(u32)hi << 32) | (u32)lo;
}

#define FDECL(i) float px##i, py##i, pz##i, dd##i = 1e10f;
#define PDECL(i) float px##i, py##i, pz##i;
#define LOADPTS(P4)                                                         \
    {   const int f4 = t * 12;                                              \
        const float4 q0 = P4[f4+0],  q1 = P4[f4+1],  q2  = P4[f4+2];        \
        const float4 q3 = P4[f4+3],  q4 = P4[f4+4],  q5  = P4[f4+5];        \
        const float4 q6 = P4[f4+6],  q7 = P4[f4+7],  q8  = P4[f4+8];        \
        const float4 q9 = P4[f4+9],  q10 = P4[f4+10], q11 = P4[f4+11];      \
        px0 =q0.x;  py0 =q0.y;  pz0 =q0.z;                                  \
        px1 =q0.w;  py1 =q1.x;  pz1 =q1.y;                                  \
        px2 =q1.z;  py2 =q1.w;  pz2 =q2.x;                                  \
        px3 =q2.y;  py3 =q2.z;  pz3 =q2.w;                                  \
        px4 =q3.x;  py4 =q3.y;  pz4 =q3.z;                                  \
        px5 =q3.w;  py5 =q4.x;  pz5 =q4.y;                                  \
        px6 =q4.z;  py6 =q4.w;  pz6 =q5.x;                                  \
        px7 =q5.y;  py7 =q5.z;  pz7 =q5.w;                                  \
        px8 =q6.x;  py8 =q6.y;  pz8 =q6.z;                                  \
        px9 =q6.w;  py9 =q7.x;  pz9 =q7.y;                                  \
        px10=q7.z;  py10=q7.w;  pz10=q8.x;                                  \
        px11=q8.y;  py11=q8.z;  pz11=q8.w;                                  \
        px12=q9.x;  py12=q9.y;  pz12=q9.z;                                  \
        px13=q9.w;  py13=q10.x; pz13=q10.y;                                 \
        px14=q10.z; py14=q10.w; pz14=q11.x;                                 \
        px15=q11.y; py15=q11.z; pz15=q11.w; }

// ---------------------------------------------------------------------------
// One kernel, three roles, all concurrent (256 blocks x 1024 thr, ~84KB LDS
// -> exactly 1 block/CU on 256 CUs -> guaranteed co-residency for spins).
//   bid <  B : FPS. Coords (48 f32) register-resident; running-min dd[] lives
//              in the (otherwise idle) hist LDS region as thread-private
//              float4 chunks dd4[c*4096 + t*4] (bank-clean, no barriers) ->
//              total live regs ~62 <= 64 -> NO per-iter L2 coord reload.
//              No coords-carry: centroid re-read via uniform scalar load
//              after the argmax. Iter 19 compute skipped. RELAXED publish.
//   bid >= B : kNN radix-select (r13 bitwise-frozen); RELAXED seed poll;
//              threadfence + done-add at end.
//   bid == B : polls done==NKNN*B-1 (init -1), fences, stats in-kernel.
// ---------------------------------------------------------------------------
__global__ __launch_bounds__(1024, 4) void fused_kernel(const float* __restrict__ pcs,
                                                        int* __restrict__ seeds,
                                                        int* __restrict__ done,
                                                        float* __restrict__ topd,
                                                        float* __restrict__ out,
                                                        int B) {
    __shared__ alignas(16) u32 hist[NBIN * NREP];   // 64KB: knn hist / fps dd[] / stats f64
    __shared__ u32   part[NBIN];
    __shared__ float cand[CAP];                     // 16 KB (also the >80KB pad)
    __shared__ u32   cnt;
    __shared__ u32   s_thr;
    __shared__ int   s_sid;
    __shared__ u64   s_key[2][16];

    const int bid  = blockIdx.x;
    const int t    = threadIdx.x;
    const int lane = t & 63;
    const int wid  = t >> 6;

    if (bid < B) {
        // ================= FPS role =================
        const float* __restrict__ P  = pcs + (size_t)bid * N_PTS * 3;
        const float4* __restrict__ P4 = (const float4*)P;

        PDECL(0)  PDECL(1)  PDECL(2)  PDECL(3)
        PDECL(4)  PDECL(5)  PDECL(6)  PDECL(7)
        PDECL(8)  PDECL(9)  PDECL(10) PDECL(11)
        PDECL(12) PDECL(13) PDECL(14) PDECL(15)
        LOADPTS(P4)

        // dd[] in LDS: thread-private float4 chunks, addr = c*16KB + t*16B.
        // Lane l -> banks (l*4..l*4+3)%32: 2-way alias on b128 = free.
        float4* __restrict__ dd4 = (float4*)hist;
#pragma unroll
        for (int c = 0; c < 4; ++c)
            dd4[c * 1024 + t] = make_float4(1e10f, 1e10f, 1e10f, 1e10f);

        float cx = P[0], cy = P[1], cz = P[2];
        int farthest = 0;

        for (int it = 0; it < N_SEEDS; ++it) {
            if (t == 0)    // RELAXED: value-only payload (r9-proven)
                __hip_atomic_store(&seeds[bid * N_SEEDS + it], farthest,
                                   __ATOMIC_RELAXED, __HIP_MEMORY_SCOPE_AGENT);
            if (it == N_SEEDS - 1) break;   // last argmax discarded by scan

            float bestv = -1.0f;
            int   besti = 0;
            // chunk c: points 4c..4c+3 ; ascending i order preserved exactly
#define FCH(c, i0, i1, i2, i3) { \
        float4 dd = dd4[c * 1024 + t]; \
        { const float dx = px##i0 - cx, dy = py##i0 - cy, dz = pz##i0 - cz; \
          const float d = (dx*dx + dy*dy) + dz*dz; \
          dd.x = fminf(dd.x, d); \
          if (dd.x > bestv) { bestv = dd.x; besti = t*16 + (i0); } } \
        { const float dx = px##i1 - cx, dy = py##i1 - cy, dz = pz##i1 - cz; \
          const float d = (dx*dx + dy*dy) + dz*dz; \
          dd.y = fminf(dd.y, d); \
          if (dd.y > bestv) { bestv = dd.y; besti = t*16 + (i1); } } \
        { const float dx = px##i2 - cx, dy = py##i2 - cy, dz = pz##i2 - cz; \
          const float d = (dx*dx + dy*dy) + dz*dz; \
          dd.z = fminf(dd.z, d); \
          if (dd.z > bestv) { bestv = dd.z; besti = t*16 + (i2); } } \
        { const float dx = px##i3 - cx, dy = py##i3 - cy, dz = pz##i3 - cz; \
          const float d = (dx*dx + dy*dy) + dz*dz; \
          dd.w = fminf(dd.w, d); \
          if (dd.w > bestv) { bestv = dd.w; besti = t*16 + (i3); } } \
        dd4[c * 1024 + t] = dd; }
            FCH(0, 0, 1, 2, 3)
            FCH(1, 4, 5, 6, 7)
            FCH(2, 8, 9, 10, 11)
            FCH(3, 12, 13, 14, 15)

            // wave max; first lane holding it (= lowest index) writes the key
            float wmax = bestv;
            for (int off = 32; off; off >>= 1)
                wmax = fmaxf(wmax, __shfl_xor(wmax, off));
            const u64 msk = __ballot(bestv == wmax);
            const int low = __ffsll((unsigned long long)msk) - 1;

            const int par = it & 1;
            if (lane == low)
                s_key[par][wid] = ((u64)__float_as_uint(wmax) << 32) | (u32)(~(u32)besti);
            __syncthreads();

            u64 k = s_key[par][lane & 15];
            for (int off = 8; off; off >>= 1) {
                const u64 o = shfl_xor_u64(k, off);
                if (o > k) k = o;
            }
            const int widx = (int)(~(u32)k);
            farthest = widx;
            // uniform centroid re-read (same bits the old coords-carry held)
            const int fi = __builtin_amdgcn_readfirstlane(widx);
            cx = P[fi*3]; cy = P[fi*3+1]; cz = P[fi*3+2];
        }
    } else {
        // ================= kNN-select role (r13 bitwise-frozen) ============
        const int kk = bid - B;
        const int b  = kk % B;          // bid ≡ b (mod 8): same XCD as fps block
        const int j  = kk / B;

        const float* __restrict__ P  = pcs + (size_t)b * N_PTS * 3;
        const float4* __restrict__ P4 = (const float4*)P;
        const int rep = t & 31;

        PDECL(0)  PDECL(1)  PDECL(2)  PDECL(3)
        PDECL(4)  PDECL(5)  PDECL(6)  PDECL(7)
        PDECL(8)  PDECL(9)  PDECL(10) PDECL(11)
        PDECL(12) PDECL(13) PDECL(14) PDECL(15)
        LOADPTS(P4)

#pragma unroll
        for (int i = 0; i < (NBIN * NREP) / 1024; ++i) hist[t + i * 1024] = 0u;
        if (t == 0) cnt = 0u;

        for (int s = j; s < N_SEEDS; s += NKNN) {
            if (t == 0) {   // RELAXED poll: seed index is the whole payload
                int sv;
                while ((sv = __hip_atomic_load(&seeds[b * N_SEEDS + s],
                               __ATOMIC_RELAXED, __HIP_MEMORY_SCOPE_AGENT)) < 0)
                    __builtin_amdgcn_s_sleep(2);
                s_sid = sv;
            }
            __syncthreads();                  // B0: sid ready, hist+cnt zeroed
            const int sid = s_sid;
            const float cx = P[sid*3], cy = P[sid*3+1], cz = P[sid*3+2];

            // ---- histogram pass (d transient) -----------------------------
#define HSTEP(i) { const float dx = px##i - cx, dy = py##i - cy, dz = pz##i - cz; \
        const float d = fmaf(dz, dz, fmaf(dy, dy, dx * dx)); \
        atomicAdd(&hist[(__float_as_uint(d) >> 22) * NREP + rep], 1u); }
            HSTEP(0)  HSTEP(1)  HSTEP(2)  HSTEP(3)
            HSTEP(4)  HSTEP(5)  HSTEP(6)  HSTEP(7)
            HSTEP(8)  HSTEP(9)  HSTEP(10) HSTEP(11)
            HSTEP(12) HSTEP(13) HSTEP(14) HSTEP(15)
            __syncthreads();                  // B1: hist complete

            if (t < NBIN) {
                u32 ssum = 0;
#pragma unroll
                for (int r = 0; r < NREP; ++r)
                    ssum += hist[t * NREP + ((r + t) & (NREP - 1))];
                part[t] = ssum;
            }
            __syncthreads();                  // B2: part[] ready

            if (wid == 0) {
                u32 s8 = 0;
#pragma unroll
                for (int i = 0; i < 8; ++i)
                    s8 += part[lane * 8 + ((i + lane) & 7)];
                u32 cum = s8;
                for (int off = 1; off < 64; off <<= 1) {
                    const u32 o = __shfl_up(cum, off);
                    if (lane >= off) cum += o;
                }
                const u64 mm = __ballot(cum >= (u32)KP1);
                const int L  = __ffsll((unsigned long long)mm) - 1;
                const u32 below = __shfl(cum - s8, L);
                const u32 bc = (lane < 8) ? part[L * 8 + lane] : 0u;
                u32 ic = bc;
                for (int off = 1; off < 8; off <<= 1) {
                    const u32 o = __shfl_up(ic, off);
                    if (lane >= off) ic += o;
                }
                const u64 mm2 = __ballot(lane < 8 && (below + ic) >= (u32)KP1);
                const int l2  = __ffsll((unsigned long long)mm2) - 1;
                if (lane == 0) s_thr = (u32)(L * 8 + l2 + 1) << 22;
            } else {
                if (t == 64) cnt = 0u;        // reset for this seed's collect
                for (int i = t - 64; i < NBIN * NREP; i += 960) hist[i] = 0u;
            }
            __syncthreads();                  // B3: thr ready, hist zeroed, cnt=0

            // ---- collect candidates (recompute d: bitwise same as HSTEP) --
            const float thrf = __uint_as_float(s_thr);
#define CSTEP(i) { const float dx = px##i - cx, dy = py##i - cy, dz = pz##i - cz; \
        const float d = fmaf(dz, dz, fmaf(dy, dy, dx * dx)); \
        if (d < thrf) { const u32 sl = atomicAdd(&cnt, 1u); \
                        if (sl < (u32)CAP) cand[sl] = d; } }
            CSTEP(0)  CSTEP(1)  CSTEP(2)  CSTEP(3)
            CSTEP(4)  CSTEP(5)  CSTEP(6)  CSTEP(7)
            CSTEP(8)  CSTEP(9)  CSTEP(10) CSTEP(11)
            CSTEP(12) CSTEP(13) CSTEP(14) CSTEP(15)
            __syncthreads();                  // B4: candidates ready

            if (wid == 0) {
                const u32 n = min(cnt, (u32)CAP);
                for (u32 base = 0; base < n; base += 64) {
                    const u32 idx = base + (u32)lane;
                    const float vv = (idx < n) ? cand[idx] : 3.0e38f;
                    u32 r = 0;
                    for (u32 jj = 0; jj < n; ++jj) {
                        const float w = cand[jj];
                        r += (w < vv || (w == vv && jj < idx)) ? 1u : 0u;
                    }
                    if (idx < n && r < (u32)KP1)
                        topd[(b * N_SEEDS + s) * KP1 + r] = sqrtf(vv);
                }
            }
        }

        // -------- signal completion (one fence per block, off hot path) ----
        __syncthreads();
        if (t == 0) {
            __threadfence();                  // make topd visible at agent scope
            __hip_atomic_fetch_add(done, 1, __ATOMIC_RELAXED,
                                   __HIP_MEMORY_SCOPE_AGENT);
        }

        // ================= stats role (block B only) =======================
        if (bid == B) {
            const int target = NKNN * B - 1;      // done init = -1 (0xFF memset)
            if (t == 0) {
                while (__hip_atomic_load(done, __ATOMIC_RELAXED,
                                         __HIP_MEMORY_SCOPE_AGENT) != target)
                    __builtin_amdgcn_s_sleep(8);
            }
            __syncthreads();
            __threadfence();    // acquire side: invalidate before topd reads

            const int pairs = B * N_SEEDS;
            const int total = pairs * KP1;
            double* red = (double*)hist;          // 8 KB scratch, hist is dead

            double s1 = 0.0;
            for (int i = t; i < total; i += 1024)
                if (i % KP1 != 0) s1 += (double)topd[i];
            red[t] = s1;
            __syncthreads();
            for (int off = 512; off; off >>= 1) {
                if (t < off) red[t] += red[t + off];
                __syncthreads();
            }
            const double om = red[0] / (double)(pairs * (KP1 - 1));

            double sm = 0.0, sm2 = 0.0;
            for (int pr = t; pr < pairs; pr += 1024) {
                double acc = 0.0;
                for (int jj = 0; jj < KP1; ++jj) acc += (double)topd[pr * KP1 + jj];
                const double m = acc / (om * (double)KP1);
                sm += m;
                sm2 += m * m;
            }
            __syncthreads();
            red[t] = sm;
            __syncthreads();
            for (int off = 512; off; off >>= 1) {
                if (t < off) red[t] += red[t + off];
                __syncthreads();
            }
            const double Sm = red[0];
            __syncthreads();
            red[t] = sm2;
            __syncthreads();
            for (int off = 512; off; off >>= 1) {
                if (t < off) red[t] += red[t + off];
                __syncthreads();
            }
            if (t == 0) {
                const double var = (red[0] - Sm * Sm / (double)pairs)
                                   / (double)(pairs - 1);
                out[0] = (float)var;
            }
        }
    }
}

// ---------------------------------------------------------------------------
extern "C" void kernel_launch(void* const* d_in, const int* in_sizes, int n_in,
                              void* d_out, int out_size, void* d_ws, size_t ws_size,
                              hipStream_t stream) {
    const float* pcs = (const float*)d_in[0];
    const int B = in_sizes[0] / (N_PTS * 3);

    int*   seeds = (int*)d_ws;                          // B*20 ints
    int*   done  = (int*)((char*)d_ws + 5120);          // 1 int, init -1
    float* topd  = (float*)((char*)d_ws + 8192);        // B*20*11 floats
    float* out   = (float*)d_out;

    // seeds -> -1, done -> -1 every launch (graph replays don't re-poison)
    (void)hipMemsetAsync(d_ws, 0xFF, 8192, stream);

    fused_kernel<<<B * (1 + NKNN), 1024, 0, stream>>>(pcs, seeds, done, topd, out, B);
}

// Round 15
// 68.177 us; speedup vs baseline: 1.0783x; 1.0783x over previous
//
#include <hip/hip_runtime.h>

#pragma clang fp contract(off)

#define N_PTS   16384
#define N_SEEDS 20
#define KP1     11      // K+1, K=10
#define NBIN    512     // bits(d2) >> 22 : exponent + 1 mantissa bit
#define NREP    32      // hist[bin*32 + (t&31)] -> bank == t&31 (conflict-free)
#define CAP     4096    // candidate buffer; also LDS pad: >80KB total -> 1 block/CU
#define NKNN    3       // knn-role blocks per batch

typedef unsigned long long u64;
typedef unsigned int       u32;

__device__ __forceinline__ u64 shfl_xor_u64(u64 v, int off) {
    int lo = __shfl_xor((int)(u32)(v & 0xffffffffull), off);
    int hi = __shfl_xor((int)(u32)(v >> 32), off);
    return ((u64)(u32)hi << 32) | (u32)lo;
}

#define FDECL(i) float px##i, py##i, pz##i, dd##i = 1e10f;
#define LOADPTS(P4)                                                         \
    {   const int f4 = t * 12;                                              \
        const float4 q0 = P4[f4+0],  q1 = P4[f4+1],  q2  = P4[f4+2];        \
        const float4 q3 = P4[f4+3],  q4 = P4[f4+4],  q5  = P4[f4+5];        \
        const float4 q6 = P4[f4+6],  q7 = P4[f4+7],  q8  = P4[f4+8];        \
        const float4 q9 = P4[f4+9],  q10 = P4[f4+10], q11 = P4[f4+11];      \
        px0 =q0.x;  py0 =q0.y;  pz0 =q0.z;                                  \
        px1 =q0.w;  py1 =q1.x;  pz1 =q1.y;                                  \
        px2 =q1.z;  py2 =q1.w;  pz2 =q2.x;                                  \
        px3 =q2.y;  py3 =q2.z;  pz3 =q2.w;                                  \
        px4 =q3.x;  py4 =q3.y;  pz4 =q3.z;                                  \
        px5 =q3.w;  py5 =q4.x;  pz5 =q4.y;                                  \
        px6 =q4.z;  py6 =q4.w;  pz6 =q5.x;                                  \
        px7 =q5.y;  py7 =q5.z;  pz7 =q5.w;                                  \
        px8 =q6.x;  py8 =q6.y;  pz8 =q6.z;                                  \
        px9 =q6.w;  py9 =q7.x;  pz9 =q7.y;                                  \
        px10=q7.z;  py10=q7.w;  pz10=q8.x;                                  \
        px11=q8.y;  py11=q8.z;  pz11=q8.w;                                  \
        px12=q9.x;  py12=q9.y;  pz12=q9.z;                                  \
        px13=q9.w;  py13=q10.x; pz13=q10.y;                                 \
        px14=q10.z; py14=q10.w; pz14=q11.x;                                 \
        px15=q11.y; py15=q11.z; pz15=q11.w; }

// ---------------------------------------------------------------------------
// One kernel, three roles, all concurrent (256 blocks x 1024 thr, ~84KB LDS
// -> exactly 1 block/CU on 256 CUs -> guaranteed co-residency for spins).
// amdgpu_waves_per_eu(4,4): LDS caps us at 4 waves/EU anyway; declaring
// min==max==4 raises the compiler's VGPR budget 64 -> 128 so the 48-float
// coord state is truly register-resident (no per-iteration L2 re-stream,
// which was ~1.3 us/iter at 64 VGPRs).
//   bid <  B : FPS for batch bid; RELAXED seed publish; winner-lane LDS
//              write; iter 19 compute skipped (argmax discarded by scan).
//   bid >= B : kNN radix-select (r8/r13-proven body, d recomputed at collect);
//              RELAXED seed poll; threadfence + done-add at end.
//   bid == B : polls done==NKNN*B-1 (init -1), fences, stats in-kernel.
// ---------------------------------------------------------------------------
__global__ __launch_bounds__(1024)
__attribute__((amdgpu_waves_per_eu(4, 4)))
void fused_kernel(const float* __restrict__ pcs,
                  int* __restrict__ seeds,
                  int* __restrict__ done,
                  float* __restrict__ topd,
                  float* __restrict__ out,
                  int B) {
    __shared__ alignas(16) u32 hist[NBIN * NREP];   // 64 KB (knn) / f64 scratch (stats)
    __shared__ u32   part[NBIN];
    __shared__ float cand[CAP];                     // 16 KB (also the >80KB pad)
    __shared__ u32   cnt;
    __shared__ u32   s_thr;
    __shared__ int   s_sid;
    __shared__ u64   s_key[2][16];                  // fps role
    __shared__ float s_cx[2][16], s_cy[2][16], s_cz[2][16];

    const int bid  = blockIdx.x;
    const int t    = threadIdx.x;
    const int lane = t & 63;
    const int wid  = t >> 6;

    if (bid < B) {
        // ================= FPS role =================
        const float* __restrict__ P  = pcs + (size_t)bid * N_PTS * 3;
        const float4* __restrict__ P4 = (const float4*)P;

        FDECL(0)  FDECL(1)  FDECL(2)  FDECL(3)
        FDECL(4)  FDECL(5)  FDECL(6)  FDECL(7)
        FDECL(8)  FDECL(9)  FDECL(10) FDECL(11)
        FDECL(12) FDECL(13) FDECL(14) FDECL(15)
        LOADPTS(P4)

        float cx = P[0], cy = P[1], cz = P[2];
        int farthest = 0;

        for (int it = 0; it < N_SEEDS; ++it) {
            if (t == 0)    // RELAXED: value-only payload (r9-proven)
                __hip_atomic_store(&seeds[bid * N_SEEDS + it], farthest,
                                   __ATOMIC_RELAXED, __HIP_MEMORY_SCOPE_AGENT);
            if (it == N_SEEDS - 1) break;   // last argmax discarded by scan

            float bestv = -1.0f, bx = 0.f, by = 0.f, bz = 0.f;
            int   besti = 0;
#define FSTEP(i) { const float dx = px##i - cx, dy = py##i - cy, dz = pz##i - cz; \
        const float d  = (dx*dx + dy*dy) + dz*dz; \
        const float nd = fminf(dd##i, d); dd##i = nd; \
        if (nd > bestv) { bestv = nd; besti = t*16 + (i); \
                          bx = px##i; by = py##i; bz = pz##i; } }
            FSTEP(0)  FSTEP(1)  FSTEP(2)  FSTEP(3)
            FSTEP(4)  FSTEP(5)  FSTEP(6)  FSTEP(7)
            FSTEP(8)  FSTEP(9)  FSTEP(10) FSTEP(11)
            FSTEP(12) FSTEP(13) FSTEP(14) FSTEP(15)

            // wave max; the first lane holding it (= lowest index) writes LDS
            float wmax = bestv;
            for (int off = 32; off; off >>= 1)
                wmax = fmaxf(wmax, __shfl_xor(wmax, off));
            const u64 msk = __ballot(bestv == wmax);
            const int low = __ffsll((unsigned long long)msk) - 1;

            const int par = it & 1;
            if (lane == low) {   // winner lane: bestv==wmax, own idx/coords
                s_key[par][wid] = ((u64)__float_as_uint(wmax) << 32) | (u32)(~(u32)besti);
                s_cx[par][wid] = bx; s_cy[par][wid] = by; s_cz[par][wid] = bz;
            }
            __syncthreads();

            u64 k = s_key[par][lane & 15];
            for (int off = 8; off; off >>= 1) {
                const u64 o = shfl_xor_u64(k, off);
                if (o > k) k = o;
            }
            const int widx = (int)(~(u32)k);
            farthest = widx;
            const int ww = widx >> 10;
            cx = s_cx[par][ww]; cy = s_cy[par][ww]; cz = s_cz[par][ww];
        }
    } else {
        // ================= kNN-select role (r13 bitwise-frozen) ============
        const int kk = bid - B;
        const int b  = kk % B;          // bid ≡ b (mod 8): same XCD as fps block
        const int j  = kk / B;

        const float* __restrict__ P  = pcs + (size_t)b * N_PTS * 3;
        const float4* __restrict__ P4 = (const float4*)P;
        const int rep = t & 31;

        FDECL(0)  FDECL(1)  FDECL(2)  FDECL(3)
        FDECL(4)  FDECL(5)  FDECL(6)  FDECL(7)
        FDECL(8)  FDECL(9)  FDECL(10) FDECL(11)
        FDECL(12) FDECL(13) FDECL(14) FDECL(15)
        LOADPTS(P4)        // dd regs unused -> DCE'd

#pragma unroll
        for (int i = 0; i < (NBIN * NREP) / 1024; ++i) hist[t + i * 1024] = 0u;
        if (t == 0) cnt = 0u;

        for (int s = j; s < N_SEEDS; s += NKNN) {
            if (t == 0) {   // RELAXED poll: seed index is the whole payload
                int sv;
                while ((sv = __hip_atomic_load(&seeds[b * N_SEEDS + s],
                               __ATOMIC_RELAXED, __HIP_MEMORY_SCOPE_AGENT)) < 0)
                    __builtin_amdgcn_s_sleep(2);
                s_sid = sv;
            }
            __syncthreads();                  // B0: sid ready, hist+cnt zeroed
            const int sid = s_sid;
            const float cx = P[sid*3], cy = P[sid*3+1], cz = P[sid*3+2];

            // ---- histogram pass (d transient) -----------------------------
#define HSTEP(i) { const float dx = px##i - cx, dy = py##i - cy, dz = pz##i - cz; \
        const float d = fmaf(dz, dz, fmaf(dy, dy, dx * dx)); \
        atomicAdd(&hist[(__float_as_uint(d) >> 22) * NREP + rep], 1u); }
            HSTEP(0)  HSTEP(1)  HSTEP(2)  HSTEP(3)
            HSTEP(4)  HSTEP(5)  HSTEP(6)  HSTEP(7)
            HSTEP(8)  HSTEP(9)  HSTEP(10) HSTEP(11)
            HSTEP(12) HSTEP(13) HSTEP(14) HSTEP(15)
            __syncthreads();                  // B1: hist complete

            if (t < NBIN) {
                u32 ssum = 0;
#pragma unroll
                for (int r = 0; r < NREP; ++r)
                    ssum += hist[t * NREP + ((r + t) & (NREP - 1))];
                part[t] = ssum;
            }
            __syncthreads();                  // B2: part[] ready

            if (wid == 0) {
                u32 s8 = 0;
#pragma unroll
                for (int i = 0; i < 8; ++i)
                    s8 += part[lane * 8 + ((i + lane) & 7)];
                u32 cum = s8;
                for (int off = 1; off < 64; off <<= 1) {
                    const u32 o = __shfl_up(cum, off);
                    if (lane >= off) cum += o;
                }
                const u64 mm = __ballot(cum >= (u32)KP1);
                const int L  = __ffsll((unsigned long long)mm) - 1;
                const u32 below = __shfl(cum - s8, L);
                const u32 bc = (lane < 8) ? part[L * 8 + lane] : 0u;
                u32 ic = bc;
                for (int off = 1; off < 8; off <<= 1) {
                    const u32 o = __shfl_up(ic, off);
                    if (lane >= off) ic += o;
                }
                const u64 mm2 = __ballot(lane < 8 && (below + ic) >= (u32)KP1);
                const int l2  = __ffsll((unsigned long long)mm2) - 1;
                if (lane == 0) s_thr = (u32)(L * 8 + l2 + 1) << 22;
            } else {
                if (t == 64) cnt = 0u;        // reset for this seed's collect
                for (int i = t - 64; i < NBIN * NREP; i += 960) hist[i] = 0u;
            }
            __syncthreads();                  // B3: thr ready, hist zeroed, cnt=0

            // ---- collect candidates (recompute d: bitwise same as HSTEP) --
            const float thrf = __uint_as_float(s_thr);
#define CSTEP(i) { const float dx = px##i - cx, dy = py##i - cy, dz = pz##i - cz; \
        const float d = fmaf(dz, dz, fmaf(dy, dy, dx * dx)); \
        if (d < thrf) { const u32 sl = atomicAdd(&cnt, 1u); \
                        if (sl < (u32)CAP) cand[sl] = d; } }
            CSTEP(0)  CSTEP(1)  CSTEP(2)  CSTEP(3)
            CSTEP(4)  CSTEP(5)  CSTEP(6)  CSTEP(7)
            CSTEP(8)  CSTEP(9)  CSTEP(10) CSTEP(11)
            CSTEP(12) CSTEP(13) CSTEP(14) CSTEP(15)
            __syncthreads();                  // B4: candidates ready

            if (wid == 0) {
                const u32 n = min(cnt, (u32)CAP);
                for (u32 base = 0; base < n; base += 64) {
                    const u32 idx = base + (u32)lane;
                    const float vv = (idx < n) ? cand[idx] : 3.0e38f;
                    u32 r = 0;
                    for (u32 jj = 0; jj < n; ++jj) {
                        const float w = cand[jj];
                        r += (w < vv || (w == vv && jj < idx)) ? 1u : 0u;
                    }
                    if (idx < n && r < (u32)KP1)
                        topd[(b * N_SEEDS + s) * KP1 + r] = sqrtf(vv);
                }
            }
        }

        // -------- signal completion (one fence per block, off hot path) ----
        __syncthreads();
        if (t == 0) {
            __threadfence();                  // make topd visible at agent scope
            __hip_atomic_fetch_add(done, 1, __ATOMIC_RELAXED,
                                   __HIP_MEMORY_SCOPE_AGENT);
        }

        // ================= stats role (block B only) =======================
        if (bid == B) {
            const int target = NKNN * B - 1;      // done init = -1 (0xFF memset)
            if (t == 0) {
                while (__hip_atomic_load(done, __ATOMIC_RELAXED,
                                         __HIP_MEMORY_SCOPE_AGENT) != target)
                    __builtin_amdgcn_s_sleep(8);
            }
            __syncthreads();
            __threadfence();    // acquire side: invalidate before topd reads

            const int pairs = B * N_SEEDS;
            const int total = pairs * KP1;
            double* red = (double*)hist;          // 8 KB scratch, hist is dead

            double s1 = 0.0;
            for (int i = t; i < total; i += 1024)
                if (i % KP1 != 0) s1 += (double)topd[i];
            red[t] = s1;
            __syncthreads();
            for (int off = 512; off; off >>= 1) {
                if (t < off) red[t] += red[t + off];
                __syncthreads();
            }
            const double om = red[0] / (double)(pairs * (KP1 - 1));

            double sm = 0.0, sm2 = 0.0;
            for (int pr = t; pr < pairs; pr += 1024) {
                double acc = 0.0;
                for (int jj = 0; jj < KP1; ++jj) acc += (double)topd[pr * KP1 + jj];
                const double m = acc / (om * (double)KP1);
                sm += m;
                sm2 += m * m;
            }
            __syncthreads();
            red[t] = sm;
            __syncthreads();
            for (int off = 512; off; off >>= 1) {
                if (t < off) red[t] += red[t + off];
                __syncthreads();
            }
            const double Sm = red[0];
            __syncthreads();
            red[t] = sm2;
            __syncthreads();
            for (int off = 512; off; off >>= 1) {
                if (t < off) red[t] += red[t + off];
                __syncthreads();
            }
            if (t == 0) {
                const double var = (red[0] - Sm * Sm / (double)pairs)
                                   / (double)(pairs - 1);
                out[0] = (float)var;
            }
        }
    }
}

// ---------------------------------------------------------------------------
extern "C" void kernel_launch(void* const* d_in, const int* in_sizes, int n_in,
                              void* d_out, int out_size, void* d_ws, size_t ws_size,
                              hipStream_t stream) {
    const float* pcs = (const float*)d_in[0];
    const int B = in_sizes[0] / (N_PTS * 3);

    int*   seeds = (int*)d_ws;                          // B*20 ints
    int*   done  = (int*)((char*)d_ws + 5120);          // 1 int, init -1
    float* topd  = (float*)((char*)d_ws + 8192);        // B*20*11 floats
    float* out   = (float*)d_out;

    // seeds -> -1, done -> -1 every launch (graph replays don't re-poison)
    (void)hipMemsetAsync(d_ws, 0xFF, 8192, stream);

    fused_kernel<<<B * (1 + NKNN), 1024, 0, stream>>>(pcs, seeds, done, topd, out, B);
}

// Round 16
// 67.321 us; speedup vs baseline: 1.0920x; 1.0127x over previous
//
#include <hip/hip_runtime.h>

#pragma clang fp contract(off)

#define N_PTS   16384
#define N_SEEDS 20
#define KP1     11      // K+1, K=10
#define NBIN    512     // bits(d2) >> 22 : exponent + 1 mantissa bit
#define NREP    32      // hist[bin*32 + (t&31)] -> bank == t&31 (conflict-free)
#define CAP     4096    // candidate buffer; also LDS pad: >80KB total -> 1 block/CU
#define NKNN    3       // knn-role blocks per batch

typedef unsigned long long u64;
typedef unsigned int       u32;

__device__ __forceinline__ u64 shfl_xor_u64(u64 v, int off) {
    int lo = __shfl_xor((int)(u32)(v & 0xffffffffull), off);
    int hi = __shfl_xor((int)(u32)(v >> 32), off);
    return ((u64)(u32)hi << 32) | (u32)lo;
}

#define FDECL(i) float px##i, py##i, pz##i, dd##i = 1e10f;
#define LOADPTS(P4)                                                         \
    {   const int f4 = t * 12;                                              \
        const float4 q0 = P4[f4+0],  q1 = P4[f4+1],  q2  = P4[f4+2];        \
        const float4 q3 = P4[f4+3],  q4 = P4[f4+4],  q5  = P4[f4+5];        \
        const float4 q6 = P4[f4+6],  q7 = P4[f4+7],  q8  = P4[f4+8];        \
        const float4 q9 = P4[f4+9],  q10 = P4[f4+10], q11 = P4[f4+11];      \
        px0 =q0.x;  py0 =q0.y;  pz0 =q0.z;                                  \
        px1 =q0.w;  py1 =q1.x;  pz1 =q1.y;                                  \
        px2 =q1.z;  py2 =q1.w;  pz2 =q2.x;                                  \
        px3 =q2.y;  py3 =q2.z;  pz3 =q2.w;                                  \
        px4 =q3.x;  py4 =q3.y;  pz4 =q3.z;                                  \
        px5 =q3.w;  py5 =q4.x;  pz5 =q4.y;                                  \
        px6 =q4.z;  py6 =q4.w;  pz6 =q5.x;                                  \
        px7 =q5.y;  py7 =q5.z;  pz7 =q5.w;                                  \
        px8 =q6.x;  py8 =q6.y;  pz8 =q6.z;                                  \
        px9 =q6.w;  py9 =q7.x;  pz9 =q7.y;                                  \
        px10=q7.z;  py10=q7.w;  pz10=q8.x;                                  \
        px11=q8.y;  py11=q8.z;  pz11=q8.w;                                  \
        px12=q9.x;  py12=q9.y;  pz12=q9.z;                                  \
        px13=q9.w;  py13=q10.x; pz13=q10.y;                                 \
        px14=q10.z; py14=q10.w; pz14=q11.x;                                 \
        px15=q11.y; py15=q11.z; pz15=q11.w; }

// Launder coord values through opaque asm: outputs can no longer be
// rematerialized from pcs -> compiler MUST keep them register-resident.
#define PIN12(a,b,c,d,e,f,g,h,i,j,k,l) \
    asm volatile("" : "+v"(a), "+v"(b), "+v"(c), "+v"(d), "+v"(e), "+v"(f), \
                      "+v"(g), "+v"(h), "+v"(i), "+v"(j), "+v"(k), "+v"(l))

// ---------------------------------------------------------------------------
// One kernel, three roles, all concurrent (256 blocks x 1024 thr, ~84KB LDS
// -> exactly 1 block/CU on 256 CUs -> guaranteed co-residency for spins).
// waves_per_eu(4,4): LDS caps us at 4 waves/EU anyway -> 128-VGPR budget.
// The fps role's 48 coord floats are PINNED via opaque asm so the scheduler
// cannot re-stream them from L2 each iteration (the ~1.4 us/iter tax that
// kept fps at 2.4 us/iter through rounds 9-15).
//   bid <  B : FPS for batch bid; RELAXED seed publish; winner-lane LDS
//              write; iter 19 compute skipped (argmax discarded by scan).
//   bid >= B : kNN radix-select (r13 bitwise-frozen, unpinned - has idle
//              slack); RELAXED seed poll; threadfence + done-add at end.
//   bid == B : polls done==NKNN*B-1 (init -1), fences, stats in-kernel.
// ---------------------------------------------------------------------------
__global__ __launch_bounds__(1024)
__attribute__((amdgpu_waves_per_eu(4, 4)))
void fused_kernel(const float* __restrict__ pcs,
                  int* __restrict__ seeds,
                  int* __restrict__ done,
                  float* __restrict__ topd,
                  float* __restrict__ out,
                  int B) {
    __shared__ alignas(16) u32 hist[NBIN * NREP];   // 64 KB (knn) / f64 scratch (stats)
    __shared__ u32   part[NBIN];
    __shared__ float cand[CAP];                     // 16 KB (also the >80KB pad)
    __shared__ u32   cnt;
    __shared__ u32   s_thr;
    __shared__ int   s_sid;
    __shared__ u64   s_key[2][16];                  // fps role
    __shared__ float s_cx[2][16], s_cy[2][16], s_cz[2][16];

    const int bid  = blockIdx.x;
    const int t    = threadIdx.x;
    const int lane = t & 63;
    const int wid  = t >> 6;

    if (bid < B) {
        // ================= FPS role =================
        const float* __restrict__ P  = pcs + (size_t)bid * N_PTS * 3;
        const float4* __restrict__ P4 = (const float4*)P;

        FDECL(0)  FDECL(1)  FDECL(2)  FDECL(3)
        FDECL(4)  FDECL(5)  FDECL(6)  FDECL(7)
        FDECL(8)  FDECL(9)  FDECL(10) FDECL(11)
        FDECL(12) FDECL(13) FDECL(14) FDECL(15)
        LOADPTS(P4)

        // pin all 48 coords: remat from memory is now illegal
        PIN12(px0, py0, pz0, px1, py1, pz1, px2, py2, pz2, px3, py3, pz3);
        PIN12(px4, py4, pz4, px5, py5, pz5, px6, py6, pz6, px7, py7, pz7);
        PIN12(px8, py8, pz8, px9, py9, pz9, px10, py10, pz10, px11, py11, pz11);
        PIN12(px12, py12, pz12, px13, py13, pz13, px14, py14, pz14, px15, py15, pz15);

        float cx = P[0], cy = P[1], cz = P[2];
        int farthest = 0;

        for (int it = 0; it < N_SEEDS; ++it) {
            if (t == 0)    // RELAXED: value-only payload (r9-proven)
                __hip_atomic_store(&seeds[bid * N_SEEDS + it], farthest,
                                   __ATOMIC_RELAXED, __HIP_MEMORY_SCOPE_AGENT);
            if (it == N_SEEDS - 1) break;   // last argmax discarded by scan

            float bestv = -1.0f, bx = 0.f, by = 0.f, bz = 0.f;
            int   besti = 0;
#define FSTEP(i) { const float dx = px##i - cx, dy = py##i - cy, dz = pz##i - cz; \
        const float d  = (dx*dx + dy*dy) + dz*dz; \
        const float nd = fminf(dd##i, d); dd##i = nd; \
        if (nd > bestv) { bestv = nd; besti = t*16 + (i); \
                          bx = px##i; by = py##i; bz = pz##i; } }
            FSTEP(0)  FSTEP(1)  FSTEP(2)  FSTEP(3)
            FSTEP(4)  FSTEP(5)  FSTEP(6)  FSTEP(7)
            FSTEP(8)  FSTEP(9)  FSTEP(10) FSTEP(11)
            FSTEP(12) FSTEP(13) FSTEP(14) FSTEP(15)

            // wave max; the first lane holding it (= lowest index) writes LDS
            float wmax = bestv;
            for (int off = 32; off; off >>= 1)
                wmax = fmaxf(wmax, __shfl_xor(wmax, off));
            const u64 msk = __ballot(bestv == wmax);
            const int low = __ffsll((unsigned long long)msk) - 1;

            const int par = it & 1;
            if (lane == low) {   // winner lane: bestv==wmax, own idx/coords
                s_key[par][wid] = ((u64)__float_as_uint(wmax) << 32) | (u32)(~(u32)besti);
                s_cx[par][wid] = bx; s_cy[par][wid] = by; s_cz[par][wid] = bz;
            }
            __syncthreads();

            u64 k = s_key[par][lane & 15];
            for (int off = 8; off; off >>= 1) {
                const u64 o = shfl_xor_u64(k, off);
                if (o > k) k = o;
            }
            const int widx = (int)(~(u32)k);
            farthest = widx;
            const int ww = widx >> 10;
            cx = s_cx[par][ww]; cy = s_cy[par][ww]; cz = s_cz[par][ww];
        }
    } else {
        // ================= kNN-select role (r13 bitwise-frozen) ============
        const int kk = bid - B;
        const int b  = kk % B;          // bid ≡ b (mod 8): same XCD as fps block
        const int j  = kk / B;

        const float* __restrict__ P  = pcs + (size_t)b * N_PTS * 3;
        const float4* __restrict__ P4 = (const float4*)P;
        const int rep = t & 31;

        FDECL(0)  FDECL(1)  FDECL(2)  FDECL(3)
        FDECL(4)  FDECL(5)  FDECL(6)  FDECL(7)
        FDECL(8)  FDECL(9)  FDECL(10) FDECL(11)
        FDECL(12) FDECL(13) FDECL(14) FDECL(15)
        LOADPTS(P4)        // dd regs unused -> DCE'd

#pragma unroll
        for (int i = 0; i < (NBIN * NREP) / 1024; ++i) hist[t + i * 1024] = 0u;
        if (t == 0) cnt = 0u;

        for (int s = j; s < N_SEEDS; s += NKNN) {
            if (t == 0) {   // RELAXED poll: seed index is the whole payload
                int sv;
                while ((sv = __hip_atomic_load(&seeds[b * N_SEEDS + s],
                               __ATOMIC_RELAXED, __HIP_MEMORY_SCOPE_AGENT)) < 0)
                    __builtin_amdgcn_s_sleep(2);
                s_sid = sv;
            }
            __syncthreads();                  // B0: sid ready, hist+cnt zeroed
            const int sid = s_sid;
            const float cx = P[sid*3], cy = P[sid*3+1], cz = P[sid*3+2];

            // ---- histogram pass (d transient) -----------------------------
#define HSTEP(i) { const float dx = px##i - cx, dy = py##i - cy, dz = pz##i - cz; \
        const float d = fmaf(dz, dz, fmaf(dy, dy, dx * dx)); \
        atomicAdd(&hist[(__float_as_uint(d) >> 22) * NREP + rep], 1u); }
            HSTEP(0)  HSTEP(1)  HSTEP(2)  HSTEP(3)
            HSTEP(4)  HSTEP(5)  HSTEP(6)  HSTEP(7)
            HSTEP(8)  HSTEP(9)  HSTEP(10) HSTEP(11)
            HSTEP(12) HSTEP(13) HSTEP(14) HSTEP(15)
            __syncthreads();                  // B1: hist complete

            if (t < NBIN) {
                u32 ssum = 0;
#pragma unroll
                for (int r = 0; r < NREP; ++r)
                    ssum += hist[t * NREP + ((r + t) & (NREP - 1))];
                part[t] = ssum;
            }
            __syncthreads();                  // B2: part[] ready

            if (wid == 0) {
                u32 s8 = 0;
#pragma unroll
                for (int i = 0; i < 8; ++i)
                    s8 += part[lane * 8 + ((i + lane) & 7)];
                u32 cum = s8;
                for (int off = 1; off < 64; off <<= 1) {
                    const u32 o = __shfl_up(cum, off);
                    if (lane >= off) cum += o;
                }
                const u64 mm = __ballot(cum >= (u32)KP1);
                const int L  = __ffsll((unsigned long long)mm) - 1;
                const u32 below = __shfl(cum - s8, L);
                const u32 bc = (lane < 8) ? part[L * 8 + lane] : 0u;
                u32 ic = bc;
                for (int off = 1; off < 8; off <<= 1) {
                    const u32 o = __shfl_up(ic, off);
                    if (lane >= off) ic += o;
                }
                const u64 mm2 = __ballot(lane < 8 && (below + ic) >= (u32)KP1);
                const int l2  = __ffsll((unsigned long long)mm2) - 1;
                if (lane == 0) s_thr = (u32)(L * 8 + l2 + 1) << 22;
            } else {
                if (t == 64) cnt = 0u;        // reset for this seed's collect
                for (int i = t - 64; i < NBIN * NREP; i += 960) hist[i] = 0u;
            }
            __syncthreads();                  // B3: thr ready, hist zeroed, cnt=0

            // ---- collect candidates (recompute d: bitwise same as HSTEP) --
            const float thrf = __uint_as_float(s_thr);
#define CSTEP(i) { const float dx = px##i - cx, dy = py##i - cy, dz = pz##i - cz; \
        const float d = fmaf(dz, dz, fmaf(dy, dy, dx * dx)); \
        if (d < thrf) { const u32 sl = atomicAdd(&cnt, 1u); \
                        if (sl < (u32)CAP) cand[sl] = d; } }
            CSTEP(0)  CSTEP(1)  CSTEP(2)  CSTEP(3)
            CSTEP(4)  CSTEP(5)  CSTEP(6)  CSTEP(7)
            CSTEP(8)  CSTEP(9)  CSTEP(10) CSTEP(11)
            CSTEP(12) CSTEP(13) CSTEP(14) CSTEP(15)
            __syncthreads();                  // B4: candidates ready

            if (wid == 0) {
                const u32 n = min(cnt, (u32)CAP);
                for (u32 base = 0; base < n; base += 64) {
                    const u32 idx = base + (u32)lane;
                    const float vv = (idx < n) ? cand[idx] : 3.0e38f;
                    u32 r = 0;
                    for (u32 jj = 0; jj < n; ++jj) {
                        const float w = cand[jj];
                        r += (w < vv || (w == vv && jj < idx)) ? 1u : 0u;
                    }
                    if (idx < n && r < (u32)KP1)
                        topd[(b * N_SEEDS + s) * KP1 + r] = sqrtf(vv);
                }
            }
        }

        // -------- signal completion (one fence per block, off hot path) ----
        __syncthreads();
        if (t == 0) {
            __threadfence();                  // make topd visible at agent scope
            __hip_atomic_fetch_add(done, 1, __ATOMIC_RELAXED,
                                   __HIP_MEMORY_SCOPE_AGENT);
        }

        // ================= stats role (block B only) =======================
        if (bid == B) {
            const int target = NKNN * B - 1;      // done init = -1 (0xFF memset)
            if (t == 0) {
                while (__hip_atomic_load(done, __ATOMIC_RELAXED,
                                         __HIP_MEMORY_SCOPE_AGENT) != target)
                    __builtin_amdgcn_s_sleep(8);
            }
            __syncthreads();
            __threadfence();    // acquire side: invalidate before topd reads

            const int pairs = B * N_SEEDS;
            const int total = pairs * KP1;
            double* red = (double*)hist;          // 8 KB scratch, hist is dead

            double s1 = 0.0;
            for (int i = t; i < total; i += 1024)
                if (i % KP1 != 0) s1 += (double)topd[i];
            red[t] = s1;
            __syncthreads();
            for (int off = 512; off; off >>= 1) {
                if (t < off) red[t] += red[t + off];
                __syncthreads();
            }
            const double om = red[0] / (double)(pairs * (KP1 - 1));

            double sm = 0.0, sm2 = 0.0;
            for (int pr = t; pr < pairs; pr += 1024) {
                double acc = 0.0;
                for (int jj = 0; jj < KP1; ++jj) acc += (double)topd[pr * KP1 + jj];
                const double m = acc / (om * (double)KP1);
                sm += m;
                sm2 += m * m;
            }
            __syncthreads();
            red[t] = sm;
            __syncthreads();
            for (int off = 512; off; off >>= 1) {
                if (t < off) red[t] += red[t + off];
                __syncthreads();
            }
            const double Sm = red[0];
            __syncthreads();
            red[t] = sm2;
            __syncthreads();
            for (int off = 512; off; off >>= 1) {
                if (t < off) red[t] += red[t + off];
                __syncthreads();
            }
            if (t == 0) {
                const double var = (red[0] - Sm * Sm / (double)pairs)
                                   / (double)(pairs - 1);
                out[0] = (float)var;
            }
        }
    }
}

// ---------------------------------------------------------------------------
extern "C" void kernel_launch(void* const* d_in, const int* in_sizes, int n_in,
                              void* d_out, int out_size, void* d_ws, size_t ws_size,
                              hipStream_t stream) {
    const float* pcs = (const float*)d_in[0];
    const int B = in_sizes[0] / (N_PTS * 3);

    int*   seeds = (int*)d_ws;                          // B*20 ints
    int*   done  = (int*)((char*)d_ws + 5120);          // 1 int, init -1
    float* topd  = (float*)((char*)d_ws + 8192);        // B*20*11 floats
    float* out   = (float*)d_out;

    // seeds -> -1, done -> -1 every launch (graph replays don't re-poison)
    (void)hipMemsetAsync(d_ws, 0xFF, 8192, stream);

    fused_kernel<<<B * (1 + NKNN), 1024, 0, stream>>>(pcs, seeds, done, topd, out, B);
}

// Round 17
// 62.341 us; speedup vs baseline: 1.1792x; 1.0799x over previous
//
#include <hip/hip_runtime.h>

#pragma clang fp contract(off)

#define N_PTS   16384
#define N_SEEDS 20
#define KP1     11      // K+1, K=10
#define NBIN    512     // bits(d2) >> 22 : exponent + 1 mantissa bit
#define NREP    32      // hist[bin*32 + (t&31)] -> bank == t&31 (conflict-free)
#define CAP     4096    // candidate buffer; also LDS pad: >80KB total -> 1 block/CU
#define NKNN    3       // knn-role blocks per batch

typedef unsigned long long u64;
typedef unsigned int       u32;

// DPP fmax step: m = fmax(m, dpp_select(m)). VALU pipe (~5cyc) instead of
// ds_swizzle (~120cyc) -> removes the per-iteration reduce stall.
#define FMAXDPP(m, ctrl, rmask) { \
    const int _v = __builtin_amdgcn_update_dpp(__float_as_int(m), __float_as_int(m), \
                                               (ctrl), (rmask), 0xf, false); \
    m = fmaxf(m, __int_as_float(_v)); }

#define FDECL(i) float px##i, py##i, pz##i, dd##i = 1e10f;
#define LOADPTS(P4)                                                         \
    {   const int f4 = t * 12;                                              \
        const float4 q0 = P4[f4+0],  q1 = P4[f4+1],  q2  = P4[f4+2];        \
        const float4 q3 = P4[f4+3],  q4 = P4[f4+4],  q5  = P4[f4+5];        \
        const float4 q6 = P4[f4+6],  q7 = P4[f4+7],  q8  = P4[f4+8];        \
        const float4 q9 = P4[f4+9],  q10 = P4[f4+10], q11 = P4[f4+11];      \
        px0 =q0.x;  py0 =q0.y;  pz0 =q0.z;                                  \
        px1 =q0.w;  py1 =q1.x;  pz1 =q1.y;                                  \
        px2 =q1.z;  py2 =q1.w;  pz2 =q2.x;                                  \
        px3 =q2.y;  py3 =q2.z;  pz3 =q2.w;                                  \
        px4 =q3.x;  py4 =q3.y;  pz4 =q3.z;                                  \
        px5 =q3.w;  py5 =q4.x;  pz5 =q4.y;                                  \
        px6 =q4.z;  py6 =q4.w;  pz6 =q5.x;                                  \
        px7 =q5.y;  py7 =q5.z;  pz7 =q5.w;                                  \
        px8 =q6.x;  py8 =q6.y;  pz8 =q6.z;                                  \
        px9 =q6.w;  py9 =q7.x;  pz9 =q7.y;                                  \
        px10=q7.z;  py10=q7.w;  pz10=q8.x;                                  \
        px11=q8.y;  py11=q8.z;  pz11=q8.w;                                  \
        px12=q9.x;  py12=q9.y;  pz12=q9.z;                                  \
        px13=q9.w;  py13=q10.x; pz13=q10.y;                                 \
        px14=q10.z; py14=q10.w; pz14=q11.x;                                 \
        px15=q11.y; py15=q11.z; pz15=q11.w; }

// ---------------------------------------------------------------------------
// One kernel, three roles, all concurrent (256 blocks x 1024 thr, ~84KB LDS
// -> exactly 1 block/CU on 256 CUs -> guaranteed co-residency for spins).
//   bid <  B : FPS. Reduce stages use DPP v_max chains (VALU) instead of
//              ds_swizzle shuffles: stage 1 = row_shr 1/2/4/8 + bcast15/31 +
//              readlane(63) (exact max; ballot + lowest-lane tie-break ==
//              first index, as r13); stage 2 = 4 row-shr over the 16 wave
//              maxima + readlane(15) + ballot + lowest-wid (ascending index
//              order), idx+coords via one ds_read_b128 (idx bit-transported
//              through float4 - no FP op touches it). RELAXED seed publish;
//              iter 19 compute skipped.
//   bid >= B : kNN radix-select (r13 bitwise-frozen); RELAXED seed poll;
//              threadfence + done-add at end.
//   bid == B : polls done==NKNN*B-1 (init -1), fences, stats in-kernel.
// ---------------------------------------------------------------------------
__global__ __launch_bounds__(1024)
__attribute__((amdgpu_waves_per_eu(4, 4)))
void fused_kernel(const float* __restrict__ pcs,
                  int* __restrict__ seeds,
                  int* __restrict__ done,
                  float* __restrict__ topd,
                  float* __restrict__ out,
                  int B) {
    __shared__ alignas(16) u32 hist[NBIN * NREP];   // 64 KB (knn) / f64 scratch (stats)
    __shared__ u32    part[NBIN];
    __shared__ float  cand[CAP];                    // 16 KB (also the >80KB pad)
    __shared__ u32    cnt;
    __shared__ u32    s_thr;
    __shared__ int    s_sid;
    __shared__ float  s_val[2][16];                 // fps: wave maxima
    __shared__ float4 s_pack[2][16];                // fps: {idx_bits, cx, cy, cz}

    const int bid  = blockIdx.x;
    const int t    = threadIdx.x;
    const int lane = t & 63;
    const int wid  = t >> 6;

    if (bid < B) {
        // ================= FPS role =================
        const float* __restrict__ P  = pcs + (size_t)bid * N_PTS * 3;
        const float4* __restrict__ P4 = (const float4*)P;

        FDECL(0)  FDECL(1)  FDECL(2)  FDECL(3)
        FDECL(4)  FDECL(5)  FDECL(6)  FDECL(7)
        FDECL(8)  FDECL(9)  FDECL(10) FDECL(11)
        FDECL(12) FDECL(13) FDECL(14) FDECL(15)
        LOADPTS(P4)

        float cx = P[0], cy = P[1], cz = P[2];
        int farthest = 0;

        for (int it = 0; it < N_SEEDS; ++it) {
            if (t == 0)    // RELAXED: value-only payload (r9-proven)
                __hip_atomic_store(&seeds[bid * N_SEEDS + it], farthest,
                                   __ATOMIC_RELAXED, __HIP_MEMORY_SCOPE_AGENT);
            if (it == N_SEEDS - 1) break;   // last argmax discarded by scan

            float bestv = -1.0f, bx = 0.f, by = 0.f, bz = 0.f;
            int   besti = 0;
#define FSTEP(i) { const float dx = px##i - cx, dy = py##i - cy, dz = pz##i - cz; \
        const float d  = (dx*dx + dy*dy) + dz*dz; \
        const float nd = fminf(dd##i, d); dd##i = nd; \
        if (nd > bestv) { bestv = nd; besti = t*16 + (i); \
                          bx = px##i; by = py##i; bz = pz##i; } }
            FSTEP(0)  FSTEP(1)  FSTEP(2)  FSTEP(3)
            FSTEP(4)  FSTEP(5)  FSTEP(6)  FSTEP(7)
            FSTEP(8)  FSTEP(9)  FSTEP(10) FSTEP(11)
            FSTEP(12) FSTEP(13) FSTEP(14) FSTEP(15)

            // ---- stage 1: wave max via DPP (bestv >= 0 always) ------------
            float m = bestv;
            FMAXDPP(m, 0x111, 0xf)   // row_shr:1
            FMAXDPP(m, 0x112, 0xf)   // row_shr:2
            FMAXDPP(m, 0x114, 0xf)   // row_shr:4
            FMAXDPP(m, 0x118, 0xf)   // row_shr:8  -> lane15 of each row = row max
            FMAXDPP(m, 0x142, 0xa)   // row_bcast:15 -> rows 1,3
            FMAXDPP(m, 0x143, 0xc)   // row_bcast:31 -> rows 2,3; lane63 = wave max
            const float wmax = __int_as_float(
                __builtin_amdgcn_readlane(__float_as_int(m), 63));
            const u64 msk = __ballot(bestv == wmax);
            const int low = __ffsll((unsigned long long)msk) - 1;

            const int par = it & 1;
            if (lane == low) {   // winner lane: lowest index holding the max
                s_val[par][wid]  = bestv;
                s_pack[par][wid] = make_float4(__int_as_float(besti), bx, by, bz);
            }
            __syncthreads();

            // ---- stage 2: max over 16 wave maxima via row-DPP -------------
            float v16 = s_val[par][lane & 15];
            float r = v16;
            FMAXDPP(r, 0x111, 0xf)
            FMAXDPP(r, 0x112, 0xf)
            FMAXDPP(r, 0x114, 0xf)
            FMAXDPP(r, 0x118, 0xf)   // lane15 (and 31,47,63) = max of 16
            const float gmax = __int_as_float(
                __builtin_amdgcn_readlane(__float_as_int(r), 15));
            const u64 m2 = __ballot(v16 == gmax) & 0xFFFFull;
            const int ws = __ffsll((unsigned long long)m2) - 1;
            const float4 pk = s_pack[par][ws];   // one b128 broadcast read
            farthest = __float_as_int(pk.x);
            cx = pk.y; cy = pk.z; cz = pk.w;
        }
    } else {
        // ================= kNN-select role (r13 bitwise-frozen) ============
        const int kk = bid - B;
        const int b  = kk % B;          // bid ≡ b (mod 8): same XCD as fps block
        const int j  = kk / B;

        const float* __restrict__ P  = pcs + (size_t)b * N_PTS * 3;
        const float4* __restrict__ P4 = (const float4*)P;
        const int rep = t & 31;

        FDECL(0)  FDECL(1)  FDECL(2)  FDECL(3)
        FDECL(4)  FDECL(5)  FDECL(6)  FDECL(7)
        FDECL(8)  FDECL(9)  FDECL(10) FDECL(11)
        FDECL(12) FDECL(13) FDECL(14) FDECL(15)
        LOADPTS(P4)        // dd regs unused -> DCE'd

#pragma unroll
        for (int i = 0; i < (NBIN * NREP) / 1024; ++i) hist[t + i * 1024] = 0u;
        if (t == 0) cnt = 0u;

        for (int s = j; s < N_SEEDS; s += NKNN) {
            if (t == 0) {   // RELAXED poll: seed index is the whole payload
                int sv;
                while ((sv = __hip_atomic_load(&seeds[b * N_SEEDS + s],
                               __ATOMIC_RELAXED, __HIP_MEMORY_SCOPE_AGENT)) < 0)
                    __builtin_amdgcn_s_sleep(2);
                s_sid = sv;
            }
            __syncthreads();                  // B0: sid ready, hist+cnt zeroed
            const int sid = s_sid;
            const float cx = P[sid*3], cy = P[sid*3+1], cz = P[sid*3+2];

            // ---- histogram pass (d transient) -----------------------------
#define HSTEP(i) { const float dx = px##i - cx, dy = py##i - cy, dz = pz##i - cz; \
        const float d = fmaf(dz, dz, fmaf(dy, dy, dx * dx)); \
        atomicAdd(&hist[(__float_as_uint(d) >> 22) * NREP + rep], 1u); }
            HSTEP(0)  HSTEP(1)  HSTEP(2)  HSTEP(3)
            HSTEP(4)  HSTEP(5)  HSTEP(6)  HSTEP(7)
            HSTEP(8)  HSTEP(9)  HSTEP(10) HSTEP(11)
            HSTEP(12) HSTEP(13) HSTEP(14) HSTEP(15)
            __syncthreads();                  // B1: hist complete

            if (t < NBIN) {
                u32 ssum = 0;
#pragma unroll
                for (int r2 = 0; r2 < NREP; ++r2)
                    ssum += hist[t * NREP + ((r2 + t) & (NREP - 1))];
                part[t] = ssum;
            }
            __syncthreads();                  // B2: part[] ready

            if (wid == 0) {
                u32 s8 = 0;
#pragma unroll
                for (int i = 0; i < 8; ++i)
                    s8 += part[lane * 8 + ((i + lane) & 7)];
                u32 cum = s8;
                for (int off = 1; off < 64; off <<= 1) {
                    const u32 o = __shfl_up(cum, off);
                    if (lane >= off) cum += o;
                }
                const u64 mm = __ballot(cum >= (u32)KP1);
                const int L  = __ffsll((unsigned long long)mm) - 1;
                const u32 below = __shfl(cum - s8, L);
                const u32 bc = (lane < 8) ? part[L * 8 + lane] : 0u;
                u32 ic = bc;
                for (int off = 1; off < 8; off <<= 1) {
                    const u32 o = __shfl_up(ic, off);
                    if (lane >= off) ic += o;
                }
                const u64 mm2 = __ballot(lane < 8 && (below + ic) >= (u32)KP1);
                const int l2  = __ffsll((unsigned long long)mm2) - 1;
                if (lane == 0) s_thr = (u32)(L * 8 + l2 + 1) << 22;
            } else {
                if (t == 64) cnt = 0u;        // reset for this seed's collect
                for (int i = t - 64; i < NBIN * NREP; i += 960) hist[i] = 0u;
            }
            __syncthreads();                  // B3: thr ready, hist zeroed, cnt=0

            // ---- collect candidates (recompute d: bitwise same as HSTEP) --
            const float thrf = __uint_as_float(s_thr);
#define CSTEP(i) { const float dx = px##i - cx, dy = py##i - cy, dz = pz##i - cz; \
        const float d = fmaf(dz, dz, fmaf(dy, dy, dx * dx)); \
        if (d < thrf) { const u32 sl = atomicAdd(&cnt, 1u); \
                        if (sl < (u32)CAP) cand[sl] = d; } }
            CSTEP(0)  CSTEP(1)  CSTEP(2)  CSTEP(3)
            CSTEP(4)  CSTEP(5)  CSTEP(6)  CSTEP(7)
            CSTEP(8)  CSTEP(9)  CSTEP(10) CSTEP(11)
            CSTEP(12) CSTEP(13) CSTEP(14) CSTEP(15)
            __syncthreads();                  // B4: candidates ready

            if (wid == 0) {
                const u32 n = min(cnt, (u32)CAP);
                for (u32 base = 0; base < n; base += 64) {
                    const u32 idx = base + (u32)lane;
                    const float vv = (idx < n) ? cand[idx] : 3.0e38f;
                    u32 r2 = 0;
                    for (u32 jj = 0; jj < n; ++jj) {
                        const float w = cand[jj];
                        r2 += (w < vv || (w == vv && jj < idx)) ? 1u : 0u;
                    }
                    if (idx < n && r2 < (u32)KP1)
                        topd[(b * N_SEEDS + s) * KP1 + r2] = sqrtf(vv);
                }
            }
        }

        // -------- signal completion (one fence per block, off hot path) ----
        __syncthreads();
        if (t == 0) {
            __threadfence();                  // make topd visible at agent scope
            __hip_atomic_fetch_add(done, 1, __ATOMIC_RELAXED,
                                   __HIP_MEMORY_SCOPE_AGENT);
        }

        // ================= stats role (block B only) =======================
        if (bid == B) {
            const int target = NKNN * B - 1;      // done init = -1 (0xFF memset)
            if (t == 0) {
                while (__hip_atomic_load(done, __ATOMIC_RELAXED,
                                         __HIP_MEMORY_SCOPE_AGENT) != target)
                    __builtin_amdgcn_s_sleep(8);
            }
            __syncthreads();
            __threadfence();    // acquire side: invalidate before topd reads

            const int pairs = B * N_SEEDS;
            const int total = pairs * KP1;
            double* red = (double*)hist;          // 8 KB scratch, hist is dead

            double s1 = 0.0;
            for (int i = t; i < total; i += 1024)
                if (i % KP1 != 0) s1 += (double)topd[i];
            red[t] = s1;
            __syncthreads();
            for (int off = 512; off; off >>= 1) {
                if (t < off) red[t] += red[t + off];
                __syncthreads();
            }
            const double om = red[0] / (double)(pairs * (KP1 - 1));

            double sm = 0.0, sm2 = 0.0;
            for (int pr = t; pr < pairs; pr += 1024) {
                double acc = 0.0;
                for (int jj = 0; jj < KP1; ++jj) acc += (double)topd[pr * KP1 + jj];
                const double m = acc / (om * (double)KP1);
                sm += m;
                sm2 += m * m;
            }
            __syncthreads();
            red[t] = sm;
            __syncthreads();
            for (int off = 512; off; off >>= 1) {
                if (t < off) red[t] += red[t + off];
                __syncthreads();
            }
            const double Sm = red[0];
            __syncthreads();
            red[t] = sm2;
            __syncthreads();
            for (int off = 512; off; off >>= 1) {
                if (t < off) red[t] += red[t + off];
                __syncthreads();
            }
            if (t == 0) {
                const double var = (red[0] - Sm * Sm / (double)pairs)
                                   / (double)(pairs - 1);
                out[0] = (float)var;
            }
        }
    }
}

// ---------------------------------------------------------------------------
extern "C" void kernel_launch(void* const* d_in, const int* in_sizes, int n_in,
                              void* d_out, int out_size, void* d_ws, size_t ws_size,
                              hipStream_t stream) {
    const float* pcs = (const float*)d_in[0];
    const int B = in_sizes[0] / (N_PTS * 3);

    int*   seeds = (int*)d_ws;                          // B*20 ints
    int*   done  = (int*)((char*)d_ws + 5120);          // 1 int, init -1
    float* topd  = (float*)((char*)d_ws + 8192);        // B*20*11 floats
    float* out   = (float*)d_out;

    // seeds -> -1, done -> -1 every launch (graph replays don't re-poison)
    (void)hipMemsetAsync(d_ws, 0xFF, 8192, stream);

    fused_kernel<<<B * (1 + NKNN), 1024, 0, stream>>>(pcs, seeds, done, topd, out, B);
}